// Round 18
// baseline (9698.931 us; speedup 1.0000x reference)
//
#include <hip/hip_runtime.h>

// LSTM 2-layer, S=512 B=64 IN=H=1024, fp32 I/O, fp16 MFMA compute.
// R18 = R17 with the wv6/7 epoch gate FIXED (R17 absmax 7e-2 post-mortem):
//   flag1=m certifies h1[m-2]; wv6/7 read h1[k-2] -> need epoch >= k,
//   NOT k-1 (R17 read layer1's recurrent operand one round early).
// Structure (unchanged): SINGLE-PHASE round, SINGLE epoch handoff/step.
//   512 thr/wg (8 waves), 256 wgs (1/CU). Round k:
//     wv0/1: x-GEMM[k]      (layer0, dep-free)      K halves
//     wv2/3: L0h  = h0[k-1] (layer0 recurrent)      epoch>=k
//     wv4/5: L1h0 = h0[k-1] (layer1 input)          epoch>=k
//     wv6/7: L1h1 = h1[k-2] (layer1 recurrent)      epoch>=k  [FIXED]
//   -> SYNC -> accL -> SYNC -> ew wv0 (h0[k]) + wv4 (h1[k-1], out[k-1])
//   -> flag0=k+1, flag1=k+1. ONE aggregation per round (wg0/wv0, the
//   dep-free wave: poll occupies its slack, publishes, then x-GEMM).
// Primitives R14-verified: asm 32-flight GEMM banks, frag-ordered weight
// LDS, sc0|sc1 h rings, relaxed flags, no fences, h0ring may alias d_out
// upper half (only out[511] collides; deferred past epoch SEQ+1).

#define SEQ   512
#define BATCH 64
#define HID   1024
#define NG    4096
#define KCAT  2048
#define F0_BASE 0            // flags0: + wg*32   (h0 side, set by wv0)
#define F1_BASE 8192         // flags1: + wg*32   (h1 side, set by wv4)
#define E_IDX   16384        // epoch replicas: + (wg&31)*32

// dynamic LDS (bytes):
//   [0,32768)       Wh0  frag-ordered (L0h,  K halves at +0 / +16384)
//   [32768,65536)   W1a  frag-ordered (L1h0, K halves)
//   [65536,98304)   W1b  frag-ordered (L1h1, K halves)
//   [98304,133120)  accL: float[2][4][64][17]
#define SMEM_BYTES 133120

typedef __attribute__((ext_vector_type(8))) _Float16 f16x8;
typedef __attribute__((ext_vector_type(4))) _Float16 f16x4;
typedef __attribute__((ext_vector_type(4))) float    f32x4;

__device__ __forceinline__ float sigm_f(float x){ return 1.f/(1.f + __expf(-x)); }
__device__ __forceinline__ float tanh_f(float x){
    float e = __expf(-2.f*fabsf(x));
    float r = (1.f - e)/(1.f + e);
    return copysignf(r, x);
}

__device__ __forceinline__ void store_h8(_Float16* p, f16x4 v){
    asm volatile("global_store_dwordx2 %0, %1, off sc0 sc1" :: "v"(p), "v"(v) : "memory");
}
__device__ __forceinline__ void drain_vmem(){
    asm volatile("s_waitcnt vmcnt(0)" ::: "memory");
}

// ---- ordered asm loads (R14-verified) ----
#define GLD(dst, base, OFF) \
    asm volatile("global_load_dwordx4 %0, %1, off offset:" #OFF \
                 : "=&v"(dst) : "v"(base))
#define GLD8L(arr, i, B) \
    GLD(arr[(i)+0],B,0);   GLD(arr[(i)+1],B,64);  GLD(arr[(i)+2],B,128); GLD(arr[(i)+3],B,192); \
    GLD(arr[(i)+4],B,256); GLD(arr[(i)+5],B,320); GLD(arr[(i)+6],B,384); GLD(arr[(i)+7],B,448)
#define GLD8H(arr, i, B) \
    GLD(arr[(i)+0],B,512); GLD(arr[(i)+1],B,576); GLD(arr[(i)+2],B,640); GLD(arr[(i)+3],B,704); \
    GLD(arr[(i)+4],B,768); GLD(arr[(i)+5],B,832); GLD(arr[(i)+6],B,896); GLD(arr[(i)+7],B,960)
#define VMWAIT0 \
    asm volatile("s_waitcnt vmcnt(0)" ::: "memory"); \
    __builtin_amdgcn_sched_barrier(0)

// ---------------- prep kernels ----------------

__global__ void prep_w_kernel(const float* __restrict__ Wx, const float* __restrict__ Wh,
                              const float* __restrict__ bx, const float* __restrict__ bh,
                              _Float16* __restrict__ Wr, float* __restrict__ br){
    int p = blockIdx.x;
    int j = p >> 2, g = p & 3;
    int r = g*1024 + j;
    int k = threadIdx.x * 8;
    const float* s = (k < 1024) ? (Wx + (size_t)r*1024 + k)
                                : (Wh + (size_t)r*1024 + (k - 1024));
    float4 v0 = *reinterpret_cast<const float4*>(s);
    float4 v1 = *reinterpret_cast<const float4*>(s + 4);
    f16x8 o;
    o[0]=(_Float16)v0.x; o[1]=(_Float16)v0.y; o[2]=(_Float16)v0.z; o[3]=(_Float16)v0.w;
    o[4]=(_Float16)v1.x; o[5]=(_Float16)v1.y; o[6]=(_Float16)v1.z; o[7]=(_Float16)v1.w;
    *reinterpret_cast<f16x8*>(Wr + (size_t)p*KCAT + k) = o;
    if (threadIdx.x == 0) br[p] = bx[r] + bh[r];
}

__global__ void prep_x_kernel(const float* __restrict__ x, _Float16* xo){
    size_t i = ((size_t)blockIdx.x*256 + threadIdx.x) * 8;
    float4 v0 = *reinterpret_cast<const float4*>(x + i);
    float4 v1 = *reinterpret_cast<const float4*>(x + i + 4);
    f16x8 o;
    o[0]=(_Float16)v0.x; o[1]=(_Float16)v0.y; o[2]=(_Float16)v0.z; o[3]=(_Float16)v0.w;
    o[4]=(_Float16)v1.x; o[5]=(_Float16)v1.y; o[6]=(_Float16)v1.z; o[7]=(_Float16)v1.w;
    *reinterpret_cast<f16x8*>(xo + i) = o;
}

__global__ void init_misc_kernel(int* flags, _Float16* hz){
    int i = blockIdx.x*256 + threadIdx.x;            // 32768 threads
    flags[i] = 0;
    if (i < 16384){
        f16x4 z; z[0]=(_Float16)0.f; z[1]=(_Float16)0.f; z[2]=(_Float16)0.f; z[3]=(_Float16)0.f;
        *reinterpret_cast<f16x4*>(hz + (size_t)i*4) = z;
    }
}

// ---------------- sync helpers (no fences) ----------------

__device__ __forceinline__ int gload(const int* p){
    return __hip_atomic_load(p, __ATOMIC_RELAXED, __HIP_MEMORY_SCOPE_AGENT);
}
__device__ __forceinline__ void gstore(int* p, int v){
    __hip_atomic_store(p, v, __ATOMIC_RELAXED, __HIP_MEMORY_SCOPE_AGENT);
}

__device__ __forceinline__ void wait_epoch_g(const int* flags, int k, int rep){
    for(;;){
        int e = gload(&flags[E_IDX + rep*32]);
        if (e >= k) break;
        __builtin_amdgcn_s_sleep(2);
    }
    asm volatile("" ::: "memory");
}

// poll BOTH flag arrays until min >= k, then publish epoch to 32 replicas
__device__ __forceinline__ void aggregate_publish_dual(int* flags, int k, int lane){
    const int b = lane*4;
    for(;;){
        int m = 0x7fffffff;
        #pragma unroll
        for (int j = 0; j < 4; ++j){
            m = min(m, gload(&flags[F0_BASE + (b+j)*32]));
            m = min(m, gload(&flags[F1_BASE + (b+j)*32]));
        }
        bool ok = (m >= k);
        if (__all(ok)) break;
        __builtin_amdgcn_s_sleep(1);
    }
    asm volatile("" ::: "memory");
    if (lane < 32)
        gstore(&flags[E_IDX + lane*32], k);
}

// ---------------- GEMM helpers (R14-verified) ----------------

__device__ __forceinline__ f32x4 mfma16(f16x8 a, f16x8 b, f32x4 c){
    return __builtin_amdgcn_mfma_f32_16x16x32_f16(a, b, c, 0, 0, 0);
}

__device__ __forceinline__ void gemm_asm_ldsb(const _Float16* A, const char* wfrag,
                                              f32x4* acc){
    const _Float16* b0 = A;
    const _Float16* b1 = A + 16*1024;
    const _Float16* b2 = A + 32*1024;
    const _Float16* b3 = A + 48*1024;
    f16x8 a[32];
    __builtin_amdgcn_sched_barrier(0);
    GLD8L(a, 0, b0); GLD8L(a, 8, b1); GLD8L(a, 16, b2); GLD8L(a, 24, b3);
    VMWAIT0;
    #pragma unroll
    for (int kk = 0; kk < 8; ++kk){
        f16x8 bb = *reinterpret_cast<const f16x8*>(wfrag + kk*1024);
        acc[0] = mfma16(a[kk],      bb, acc[0]);
        acc[1] = mfma16(a[8 + kk],  bb, acc[1]);
        acc[2] = mfma16(a[16 + kk], bb, acc[2]);
        acc[3] = mfma16(a[24 + kk], bb, acc[3]);
    }
    __builtin_amdgcn_sched_barrier(0);
    GLD8H(a, 0, b0); GLD8H(a, 8, b1); GLD8H(a, 16, b2); GLD8H(a, 24, b3);
    VMWAIT0;
    #pragma unroll
    for (int kk = 0; kk < 8; ++kk){
        f16x8 bb = *reinterpret_cast<const f16x8*>(wfrag + (8 + kk)*1024);
        acc[0] = mfma16(a[kk],      bb, acc[0]);
        acc[1] = mfma16(a[8 + kk],  bb, acc[1]);
        acc[2] = mfma16(a[16 + kk], bb, acc[2]);
        acc[3] = mfma16(a[24 + kk], bb, acc[3]);
    }
    __builtin_amdgcn_sched_barrier(0);
}

__device__ __forceinline__ void gemm_asm_gb(const _Float16* A, const _Float16* Wp,
                                            f32x4* acc){
    const _Float16* b0 = A;
    const _Float16* b1 = A + 16*1024;
    const _Float16* b2 = A + 32*1024;
    const _Float16* b3 = A + 48*1024;
    f16x8 bw[8], a[32];
    __builtin_amdgcn_sched_barrier(0);
    GLD8L(bw, 0, Wp);
    GLD8L(a, 0, b0); GLD8L(a, 8, b1); GLD8L(a, 16, b2); GLD8L(a, 24, b3);
    VMWAIT0;
    #pragma unroll
    for (int kk = 0; kk < 8; ++kk){
        acc[0] = mfma16(a[kk],      bw[kk], acc[0]);
        acc[1] = mfma16(a[8 + kk],  bw[kk], acc[1]);
        acc[2] = mfma16(a[16 + kk], bw[kk], acc[2]);
        acc[3] = mfma16(a[24 + kk], bw[kk], acc[3]);
    }
    __builtin_amdgcn_sched_barrier(0);
    GLD8H(bw, 0, Wp);
    GLD8H(a, 0, b0); GLD8H(a, 8, b1); GLD8H(a, 16, b2); GLD8H(a, 24, b3);
    VMWAIT0;
    #pragma unroll
    for (int kk = 0; kk < 8; ++kk){
        acc[0] = mfma16(a[kk],      bw[kk], acc[0]);
        acc[1] = mfma16(a[8 + kk],  bw[kk], acc[1]);
        acc[2] = mfma16(a[16 + kk], bw[kk], acc[2]);
        acc[3] = mfma16(a[24 + kk], bw[kk], acc[3]);
    }
    __builtin_amdgcn_sched_barrier(0);
}

__device__ __forceinline__ void gemm_q_f32(const float* A, const _Float16* Wp, f32x4* acc){
    #pragma unroll 2
    for (int kk = 0; kk < 16; ++kk){
        f16x8 b = *reinterpret_cast<const f16x8*>(Wp + kk*32);
        f16x8 a[4];
        #pragma unroll
        for (int m = 0; m < 4; ++m){
            float4 u0 = *reinterpret_cast<const float4*>(A + kk*32 + (size_t)m*16*1024);
            float4 u1 = *reinterpret_cast<const float4*>(A + kk*32 + (size_t)m*16*1024 + 4);
            f16x8 v;
            v[0]=(_Float16)u0.x; v[1]=(_Float16)u0.y; v[2]=(_Float16)u0.z; v[3]=(_Float16)u0.w;
            v[4]=(_Float16)u1.x; v[5]=(_Float16)u1.y; v[6]=(_Float16)u1.z; v[7]=(_Float16)u1.w;
            a[m] = v;
        }
        acc[0] = mfma16(a[0], b, acc[0]);
        acc[1] = mfma16(a[1], b, acc[1]);
        acc[2] = mfma16(a[2], b, acc[2]);
        acc[3] = mfma16(a[3], b, acc[3]);
    }
}

// ---------------- persistent LSTM kernel ----------------

__global__ __launch_bounds__(512, 1)
void lstm_persist(const _Float16* __restrict__ Wr0, const _Float16* __restrict__ Wr1,
                  const float* __restrict__ br0, const float* __restrict__ br1,
                  const _Float16* __restrict__ xbf, const float* __restrict__ xf32,
                  int use_xf16, const _Float16* __restrict__ hz,
                  _Float16* h0ring, _Float16* h1ring, float* out, int* flags){
    extern __shared__ char smem[];
    float (*accL)[4][64][17] = reinterpret_cast<float(*)[4][64][17]>(smem + 98304);

    const int tid  = threadIdx.x;
    const int wg   = blockIdx.x;          // 0..255
    const int wv   = tid >> 6;            // 0..7
    const int lane = tid & 63;
    const int r    = lane & 15;
    const int q    = lane >> 4;
    const int p0   = wg * 16;
    const int rep  = wg & 31;
    const int kh   = wv & 1;              // K-half within the wave pair
    const size_t BH = (size_t)BATCH*HID;

    // stage recurrent-path weights, FRAG-ORDERED (identical layout to R14)
    for (int idx = tid; idx < 6144; idx += 512){
        const _Float16* s; char* dst;
        if (idx < 2048){                     // Wh0 (L0h): Wr0 cols 1024..2047
            int wvh = idx >> 10, kk = (idx >> 6) & 15, ln = idx & 63;
            s = Wr0 + (size_t)(p0 + (ln & 15))*KCAT + 1024 + wvh*512 + kk*32 + (ln >> 4)*8;
            dst = smem + idx*16;
        } else {                             // W1: Wr1 cols 0..2047 (quarters)
            int d = idx - 2048;
            int wvd = d >> 10, kk = (d >> 6) & 15, ln = d & 63;
            s = Wr1 + (size_t)(p0 + (ln & 15))*KCAT + wvd*512 + kk*32 + (ln >> 4)*8;
            dst = smem + 32768 + d*16;
        }
        *reinterpret_cast<f16x8*>(dst) = *reinterpret_cast<const f16x8*>(s);
    }
    __syncthreads();

    f32x4 cst = {0.f,0.f,0.f,0.f};        // wv0: c layer0; wv4: c layer1
    f32x4 ho_keep = {0.f,0.f,0.f,0.f};    // wv4: out[511] deferred
    f32x4 bias[4];
    {
        const float* bsrc = (wv == 0) ? br0 : br1;
        #pragma unroll
        for (int jj = 0; jj < 4; ++jj)
            bias[jj] = *reinterpret_cast<const f32x4*>(&bsrc[p0 + jj*4]);
    }

    const int kofs = kh*512 + q*8;
    // LDS weight fragment base per wave pair
    const char* wfrag =
        (wv < 4) ? (smem + kh*16384 + lane*16)                    // wv2/3: Wh0
                 : (wv < 6) ? (smem + 32768 + kh*16384 + lane*16) // wv4/5: W1 cols 0..1023
                            : (smem + 65536 + kh*16384 + lane*16);// wv6/7: W1 cols 1024..2047

    for (int k = 0; k <= SEQ; ++k){
        f32x4 acc[4];
        #pragma unroll
        for (int m = 0; m < 4; ++m){ acc[m].x=0;acc[m].y=0;acc[m].z=0;acc[m].w=0; }

        // ---- epoch gate + aggregation (single handoff per round) ----
        if (k > 0){
            if (wg == 0 && wv == 0)      aggregate_publish_dual(flags, k, lane);
            else if (wv >= 2 && wv < 6)  wait_epoch_g(flags, k, rep);     // h0[k-1]
            else if (wv >= 6 && k >= 2)  wait_epoch_g(flags, k, rep);     // h1[k-2] — FIXED (flag1=k certifies h1[k-2])
        }

        // ---- this wave's GEMM (K=512 slice) ----
        if (wv < 2){                          // x-GEMM, layer0
            if (k < SEQ){
                if (use_xf16)
                    gemm_asm_gb(xbf + (size_t)k*BH + (size_t)r*HID + kofs,
                                Wr0 + (size_t)(p0 + r)*KCAT + kh*512 + q*8, acc);
                else
                    gemm_q_f32(xf32 + (size_t)k*BH + (size_t)r*HID + kofs,
                               Wr0 + (size_t)(p0 + r)*KCAT + kh*512 + q*8, acc);
            }
        } else if (wv < 4){                   // L0h, layer0
            if (k < SEQ){
                const _Float16* A = (k == 0) ? (hz + (size_t)r*HID + kofs)
                                             : (h0ring + (size_t)(k-1)*BH + (size_t)r*HID + kofs);
                gemm_asm_ldsb(A, wfrag, acc);
            }
        } else if (wv < 6){                   // L1h0, layer1
            if (k >= 1)
                gemm_asm_ldsb(h0ring + (size_t)(k-1)*BH + (size_t)r*HID + kofs, wfrag, acc);
        } else {                              // L1h1, layer1
            if (k >= 1){
                const _Float16* A = (k == 1) ? (hz + (size_t)r*HID + kofs)
                                             : (h1ring + (size_t)(k-2)*BH + (size_t)r*HID + kofs);
                gemm_asm_ldsb(A, wfrag, acc);
            }
        }

        __syncthreads();   // SYNC_B: previous round's ew reads of accL complete

        #pragma unroll
        for (int mt = 0; mt < 4; ++mt)
            #pragma unroll
            for (int j = 0; j < 4; ++j)
                accL[wv >> 2][wv & 3][mt*16 + q*4 + j][r] = acc[mt][j];
        __syncthreads();   // SYNC_A: all contributions visible

        if (wv == 0 && k < SEQ){
            // elementwise layer0: lane = batch row, 4 h-cols
            f32x4 zz[4];
            #pragma unroll
            for (int jj = 0; jj < 4; ++jj) zz[jj] = bias[jj];
            #pragma unroll
            for (int c = 0; c < 4; ++c)
                #pragma unroll
                for (int jj = 0; jj < 4; ++jj){
                    f32x4 a = *reinterpret_cast<const f32x4*>(&accL[0][c][lane][jj*4]);
                    zz[jj].x += a.x; zz[jj].y += a.y; zz[jj].z += a.z; zz[jj].w += a.w;
                }
            f16x4 hv;
            #pragma unroll
            for (int jl = 0; jl < 4; ++jl){
                float ig = sigm_f(zz[jl].x), fg = sigm_f(zz[jl].y);
                float gg = tanh_f(zz[jl].z), og = sigm_f(zz[jl].w);
                float c = fg*cst[jl] + ig*gg;  cst[jl] = c;
                hv[jl] = (_Float16)(og * tanh_f(c));
            }
            store_h8(h0ring + ((size_t)k*BATCH + lane)*HID + wg*4, hv);
            drain_vmem();
            if (lane == 0) gstore(&flags[F0_BASE + wg*32], k + 1);
        }

        if (wv == 4){
            if (k >= 1){
                const int t1 = k - 1;
                f32x4 zz[4];
                #pragma unroll
                for (int jj = 0; jj < 4; ++jj) zz[jj] = bias[jj];
                #pragma unroll
                for (int c = 0; c < 4; ++c)
                    #pragma unroll
                    for (int jj = 0; jj < 4; ++jj){
                        f32x4 a = *reinterpret_cast<const f32x4*>(&accL[1][c][lane][jj*4]);
                        zz[jj].x += a.x; zz[jj].y += a.y; zz[jj].z += a.z; zz[jj].w += a.w;
                    }
                f16x4 hv; f32x4 ho;
                #pragma unroll
                for (int jl = 0; jl < 4; ++jl){
                    float ig = sigm_f(zz[jl].x), fg = sigm_f(zz[jl].y);
                    float gg = tanh_f(zz[jl].z), og = sigm_f(zz[jl].w);
                    float c = fg*cst[jl] + ig*gg;  cst[jl] = c;
                    float h = og * tanh_f(c);
                    hv[jl] = (_Float16)h;  ho[jl] = h;
                }
                if (k < SEQ) store_h8(h1ring + ((size_t)t1*BATCH + lane)*HID + wg*4, hv);
                if (t1 < SEQ-1) *reinterpret_cast<f32x4*>(out + ((size_t)t1*BATCH + lane)*HID + wg*4) = ho;
                else            ho_keep = ho;   // out[511] deferred (alias safety)
                drain_vmem();
            }
            if (lane == 0) gstore(&flags[F1_BASE + wg*32], k + 1);
        }
    }

    // epilogue: flag0=SEQ+1 (all this wg's h0[511] reads done at final SYNC_A);
    // aggregator publishes epoch SEQ+1; wv4 then writes out[511].
    if (tid == 0) gstore(&flags[F0_BASE + wg*32], SEQ + 1);
    if (wg == 0 && wv == 0) aggregate_publish_dual(flags, SEQ + 1, lane);
    if (wv == 4){
        wait_epoch_g(flags, SEQ + 1, rep);
        *reinterpret_cast<f32x4*>(out + ((size_t)(SEQ-1)*BATCH + lane)*HID + wg*4) = ho_keep;
    }
}

// ---------------- host launcher ----------------

extern "C" void kernel_launch(void* const* d_in, const int* in_sizes, int n_in,
                              void* d_out, int out_size, void* d_ws, size_t ws_size,
                              hipStream_t stream){
    const float* x   = (const float*)d_in[0];
    const float* Wx0 = (const float*)d_in[1];
    const float* bx0 = (const float*)d_in[2];
    const float* Wh0 = (const float*)d_in[3];
    const float* bh0 = (const float*)d_in[4];
    const float* Wx1 = (const float*)d_in[5];
    const float* bx1 = (const float*)d_in[6];
    const float* Wh1 = (const float*)d_in[7];
    const float* bh1 = (const float*)d_in[8];
    float* out = (float*)d_out;
    char* ws = (char*)d_ws;

    size_t o = 0;
    _Float16* Wr0 = (_Float16*)(ws + o); o += (size_t)NG*KCAT*2;
    _Float16* Wr1 = (_Float16*)(ws + o); o += (size_t)NG*KCAT*2;
    float* br0 = (float*)(ws + o); o += 16384;
    float* br1 = (float*)(ws + o); o += 16384;
    _Float16* h1ring = (_Float16*)(ws + o); o += (size_t)SEQ*BATCH*HID*2;
    _Float16* hz     = (_Float16*)(ws + o); o += (size_t)BATCH*HID*2;
    int* flags = (int*)(ws + o); o += 131072;

    const size_t RING = (size_t)SEQ*BATCH*HID*2;
    _Float16 *xbf = nullptr, *h0ring;
    int use_xf16 = 0;
    if (ws_size >= o + 2*RING){
        xbf    = (_Float16*)(ws + o);  o += RING;  use_xf16 = 1;
        h0ring = (_Float16*)(ws + o);  o += RING;
    } else if (ws_size >= o + RING){
        xbf    = (_Float16*)(ws + o);  o += RING;  use_xf16 = 1;
        h0ring = (_Float16*)((char*)d_out + (size_t)64*1024*1024);
    } else {
        h0ring = (_Float16*)((char*)d_out + (size_t)64*1024*1024);
    }

    hipFuncSetAttribute((const void*)lstm_persist,
                        hipFuncAttributeMaxDynamicSharedMemorySize, SMEM_BYTES);

    prep_w_kernel<<<NG, 256, 0, stream>>>(Wx0, Wh0, bx0, bh0, Wr0, br0);
    prep_w_kernel<<<NG, 256, 0, stream>>>(Wx1, Wh1, bx1, bh1, Wr1, br1);
    if (use_xf16)
        prep_x_kernel<<<(SEQ*BATCH*HID)/(256*8), 256, 0, stream>>>(x, xbf);
    init_misc_kernel<<<128, 256, 0, stream>>>(flags, hz);
    lstm_persist<<<256, 512, SMEM_BYTES, stream>>>(Wr0, Wr1, br0, br1, xbf, x, use_xf16,
                                                   hz, h0ring, h1ring, out, flags);
}

// Round 19
// 8772.778 us; speedup vs baseline: 1.1056x; 1.1056x over previous
//
#include <hip/hip_runtime.h>

// LSTM 2-layer, S=512 B=64 IN=H=1024, fp32 I/O, fp16 MFMA compute.
// R19 = R14 restored byte-identical (session best: 8.76 ms).
// Rationale: R9-R18 falsified every candidate dominant term (handoff count,
// aggregator placement, comms-wave, layer-split, MLP depth) — round time
// ~17-19us is a sync/latency plateau of this decomposition family; R14 is
// its verified optimum. Structure: merged two-phase round, 256 thr, asm-MLP
// 32-flight GEMM banks (vmcnt(0), sched_barrier-fenced), frag-ordered weight
// LDS, top-of-phase aggregation by wg0, sc0|sc1 h rings, relaxed flags.

#define SEQ   512
#define BATCH 64
#define HID   1024
#define NG    4096
#define KCAT  2048
#define F0_BASE 0            // flags0: + wg*32
#define E0_IDX  8192         // epoch0 replicas: + (wg&31)*32
#define F1_BASE 16384        // flags1: + wg*32
#define E1_IDX  24576        // epoch1 replicas: + (wg&31)*32

// dynamic LDS (bytes):
//   [0,32768)       Wh0 frag-ordered: (wvh,kk,lane) -> wvh*16384+kk*1024+lane*16
//   [32768,98304)   W1  frag-ordered: (wv,kk,lane)  -> 32768+wv*16384+kk*1024+lane*16
//   [98304,133120)  accL: float[2][4][64][17]
#define SMEM_BYTES 133120

typedef __attribute__((ext_vector_type(8))) _Float16 f16x8;
typedef __attribute__((ext_vector_type(4))) _Float16 f16x4;
typedef __attribute__((ext_vector_type(4))) float    f32x4;

__device__ __forceinline__ float sigm_f(float x){ return 1.f/(1.f + __expf(-x)); }
__device__ __forceinline__ float tanh_f(float x){
    float e = __expf(-2.f*fabsf(x));
    float r = (1.f - e)/(1.f + e);
    return copysignf(r, x);
}

__device__ __forceinline__ void store_h8(_Float16* p, f16x4 v){
    asm volatile("global_store_dwordx2 %0, %1, off sc0 sc1" :: "v"(p), "v"(v) : "memory");
}
__device__ __forceinline__ void drain_vmem(){
    asm volatile("s_waitcnt vmcnt(0)" ::: "memory");
}

// ---- ordered asm loads ----
#define GLD(dst, base, OFF) \
    asm volatile("global_load_dwordx4 %0, %1, off offset:" #OFF \
                 : "=&v"(dst) : "v"(base))
#define GLD8L(arr, i, B) \
    GLD(arr[(i)+0],B,0);   GLD(arr[(i)+1],B,64);  GLD(arr[(i)+2],B,128); GLD(arr[(i)+3],B,192); \
    GLD(arr[(i)+4],B,256); GLD(arr[(i)+5],B,320); GLD(arr[(i)+6],B,384); GLD(arr[(i)+7],B,448)
#define GLD8H(arr, i, B) \
    GLD(arr[(i)+0],B,512); GLD(arr[(i)+1],B,576); GLD(arr[(i)+2],B,640); GLD(arr[(i)+3],B,704); \
    GLD(arr[(i)+4],B,768); GLD(arr[(i)+5],B,832); GLD(arr[(i)+6],B,896); GLD(arr[(i)+7],B,960)
#define VMWAIT0 \
    asm volatile("s_waitcnt vmcnt(0)" ::: "memory"); \
    __builtin_amdgcn_sched_barrier(0)

// ---------------- prep kernels ----------------

__global__ void prep_w_kernel(const float* __restrict__ Wx, const float* __restrict__ Wh,
                              const float* __restrict__ bx, const float* __restrict__ bh,
                              _Float16* __restrict__ Wr, float* __restrict__ br){
    int p = blockIdx.x;
    int j = p >> 2, g = p & 3;
    int r = g*1024 + j;
    int k = threadIdx.x * 8;
    const float* s = (k < 1024) ? (Wx + (size_t)r*1024 + k)
                                : (Wh + (size_t)r*1024 + (k - 1024));
    float4 v0 = *reinterpret_cast<const float4*>(s);
    float4 v1 = *reinterpret_cast<const float4*>(s + 4);
    f16x8 o;
    o[0]=(_Float16)v0.x; o[1]=(_Float16)v0.y; o[2]=(_Float16)v0.z; o[3]=(_Float16)v0.w;
    o[4]=(_Float16)v1.x; o[5]=(_Float16)v1.y; o[6]=(_Float16)v1.z; o[7]=(_Float16)v1.w;
    *reinterpret_cast<f16x8*>(Wr + (size_t)p*KCAT + k) = o;
    if (threadIdx.x == 0) br[p] = bx[r] + bh[r];
}

__global__ void prep_x_kernel(const float* __restrict__ x, _Float16* xo){
    size_t i = ((size_t)blockIdx.x*256 + threadIdx.x) * 8;
    float4 v0 = *reinterpret_cast<const float4*>(x + i);
    float4 v1 = *reinterpret_cast<const float4*>(x + i + 4);
    f16x8 o;
    o[0]=(_Float16)v0.x; o[1]=(_Float16)v0.y; o[2]=(_Float16)v0.z; o[3]=(_Float16)v0.w;
    o[4]=(_Float16)v1.x; o[5]=(_Float16)v1.y; o[6]=(_Float16)v1.z; o[7]=(_Float16)v1.w;
    *reinterpret_cast<f16x8*>(xo + i) = o;
}

__global__ void init_misc_kernel(int* flags, _Float16* hz){
    int i = blockIdx.x*256 + threadIdx.x;            // 32768 threads
    flags[i] = 0;
    if (i < 16384){
        f16x4 z; z[0]=(_Float16)0.f; z[1]=(_Float16)0.f; z[2]=(_Float16)0.f; z[3]=(_Float16)0.f;
        *reinterpret_cast<f16x4*>(hz + (size_t)i*4) = z;
    }
}

// ---------------- sync helpers (no fences) ----------------

__device__ __forceinline__ void wait_epoch_g(const int* flags, int eidx, int k, int rep){
    for(;;){
        int e = __hip_atomic_load(&flags[eidx + rep*32], __ATOMIC_RELAXED, __HIP_MEMORY_SCOPE_AGENT);
        if (e >= k) break;
        __builtin_amdgcn_s_sleep(2);
    }
    asm volatile("" ::: "memory");
}

__device__ __forceinline__ void aggregate_publish(int* flags, int base, int eidx,
                                                  int k, int lane){
    const int b = lane*4;
    for(;;){
        int a0 = __hip_atomic_load(&flags[base + (b+0)*32], __ATOMIC_RELAXED, __HIP_MEMORY_SCOPE_AGENT);
        int a1 = __hip_atomic_load(&flags[base + (b+1)*32], __ATOMIC_RELAXED, __HIP_MEMORY_SCOPE_AGENT);
        int a2 = __hip_atomic_load(&flags[base + (b+2)*32], __ATOMIC_RELAXED, __HIP_MEMORY_SCOPE_AGENT);
        int a3 = __hip_atomic_load(&flags[base + (b+3)*32], __ATOMIC_RELAXED, __HIP_MEMORY_SCOPE_AGENT);
        bool ok = (a0>=k) && (a1>=k) && (a2>=k) && (a3>=k);
        if (__all(ok)) break;
        __builtin_amdgcn_s_sleep(1);
    }
    asm volatile("" ::: "memory");
    if (lane < 32)
        __hip_atomic_store(&flags[eidx + lane*32], k, __ATOMIC_RELAXED, __HIP_MEMORY_SCOPE_AGENT);
}

// ---------------- GEMM helpers ----------------

__device__ __forceinline__ f32x4 mfma16(f16x8 a, f16x8 b, f32x4 c){
    return __builtin_amdgcn_mfma_f32_16x16x32_f16(a, b, c, 0, 0, 0);
}

// A via asm loads, 32-flight banks, vmcnt(0) only; B from frag-ordered LDS.
__device__ __forceinline__ void gemm_asm_ldsb(const _Float16* A, const char* wfrag,
                                              f32x4* acc){
    const _Float16* b0 = A;
    const _Float16* b1 = A + 16*1024;
    const _Float16* b2 = A + 32*1024;
    const _Float16* b3 = A + 48*1024;
    f16x8 a[32];
    __builtin_amdgcn_sched_barrier(0);
    GLD8L(a, 0, b0); GLD8L(a, 8, b1); GLD8L(a, 16, b2); GLD8L(a, 24, b3);   // kk 0..7
    VMWAIT0;
    #pragma unroll
    for (int kk = 0; kk < 8; ++kk){
        f16x8 bb = *reinterpret_cast<const f16x8*>(wfrag + kk*1024);
        acc[0] = mfma16(a[kk],      bb, acc[0]);
        acc[1] = mfma16(a[8 + kk],  bb, acc[1]);
        acc[2] = mfma16(a[16 + kk], bb, acc[2]);
        acc[3] = mfma16(a[24 + kk], bb, acc[3]);
    }
    __builtin_amdgcn_sched_barrier(0);
    GLD8H(a, 0, b0); GLD8H(a, 8, b1); GLD8H(a, 16, b2); GLD8H(a, 24, b3);   // kk 8..15
    VMWAIT0;
    #pragma unroll
    for (int kk = 0; kk < 8; ++kk){
        f16x8 bb = *reinterpret_cast<const f16x8*>(wfrag + (8 + kk)*1024);
        acc[0] = mfma16(a[kk],      bb, acc[0]);
        acc[1] = mfma16(a[8 + kk],  bb, acc[1]);
        acc[2] = mfma16(a[16 + kk], bb, acc[2]);
        acc[3] = mfma16(a[24 + kk], bb, acc[3]);
    }
    __builtin_amdgcn_sched_barrier(0);
}

// A + B via asm loads (B from global, L2-resident x-weights), same banking.
__device__ __forceinline__ void gemm_asm_gb(const _Float16* A, const _Float16* Wp,
                                            f32x4* acc){
    const _Float16* b0 = A;
    const _Float16* b1 = A + 16*1024;
    const _Float16* b2 = A + 32*1024;
    const _Float16* b3 = A + 48*1024;
    f16x8 bw[8], a[32];
    __builtin_amdgcn_sched_barrier(0);
    GLD8L(bw, 0, Wp);                                                        // B kk 0..7
    GLD8L(a, 0, b0); GLD8L(a, 8, b1); GLD8L(a, 16, b2); GLD8L(a, 24, b3);    // A kk 0..7
    VMWAIT0;
    #pragma unroll
    for (int kk = 0; kk < 8; ++kk){
        acc[0] = mfma16(a[kk],      bw[kk], acc[0]);
        acc[1] = mfma16(a[8 + kk],  bw[kk], acc[1]);
        acc[2] = mfma16(a[16 + kk], bw[kk], acc[2]);
        acc[3] = mfma16(a[24 + kk], bw[kk], acc[3]);
    }
    __builtin_amdgcn_sched_barrier(0);
    GLD8H(bw, 0, Wp);                                                        // B kk 8..15
    GLD8H(a, 0, b0); GLD8H(a, 8, b1); GLD8H(a, 16, b2); GLD8H(a, 24, b3);    // A kk 8..15
    VMWAIT0;
    #pragma unroll
    for (int kk = 0; kk < 8; ++kk){
        acc[0] = mfma16(a[kk],      bw[kk], acc[0]);
        acc[1] = mfma16(a[8 + kk],  bw[kk], acc[1]);
        acc[2] = mfma16(a[16 + kk], bw[kk], acc[2]);
        acc[3] = mfma16(a[24 + kk], bw[kk], acc[3]);
    }
    __builtin_amdgcn_sched_barrier(0);
}

// f32 x fallback (only when ws too small for xbf)
__device__ __forceinline__ void gemm_q_f32(const float* A, const _Float16* Wp, f32x4* acc){
    #pragma unroll 2
    for (int kk = 0; kk < 16; ++kk){
        f16x8 b = *reinterpret_cast<const f16x8*>(Wp + kk*32);
        f16x8 a[4];
        #pragma unroll
        for (int m = 0; m < 4; ++m){
            float4 u0 = *reinterpret_cast<const float4*>(A + kk*32 + (size_t)m*16*1024);
            float4 u1 = *reinterpret_cast<const float4*>(A + kk*32 + (size_t)m*16*1024 + 4);
            f16x8 v;
            v[0]=(_Float16)u0.x; v[1]=(_Float16)u0.y; v[2]=(_Float16)u0.z; v[3]=(_Float16)u0.w;
            v[4]=(_Float16)u1.x; v[5]=(_Float16)u1.y; v[6]=(_Float16)u1.z; v[7]=(_Float16)u1.w;
            a[m] = v;
        }
        acc[0] = mfma16(a[0], b, acc[0]);
        acc[1] = mfma16(a[1], b, acc[1]);
        acc[2] = mfma16(a[2], b, acc[2]);
        acc[3] = mfma16(a[3], b, acc[3]);
    }
}

// ---------------- persistent LSTM kernel ----------------

__global__ __launch_bounds__(256, 1)
void lstm_persist(const _Float16* __restrict__ Wr0, const _Float16* __restrict__ Wr1,
                  const float* __restrict__ br0, const float* __restrict__ br1,
                  const _Float16* __restrict__ xbf, const float* __restrict__ xf32,
                  int use_xf16, const _Float16* __restrict__ hz,
                  _Float16* h0ring, _Float16* h1ring, float* out, int* flags){
    extern __shared__ char smem[];
    float (*accL)[4][64][17] = reinterpret_cast<float(*)[4][64][17]>(smem + 98304);

    const int tid  = threadIdx.x;
    const int wg   = blockIdx.x;
    const int wv   = tid >> 6;
    const int lane = tid & 63;
    const int r    = lane & 15;
    const int q    = lane >> 4;
    const int p0   = wg * 16;
    const int rep  = wg & 31;

    // stage recurrent-path weights, FRAG-ORDERED
    for (int idx = tid; idx < 6144; idx += 256){
        const _Float16* s; char* dst;
        if (idx < 2048){                     // Wh0
            int wvh = idx >> 10, kk = (idx >> 6) & 15, ln = idx & 63;
            s = Wr0 + (size_t)(p0 + (ln & 15))*KCAT + 1024 + wvh*512 + kk*32 + (ln >> 4)*8;
            dst = smem + idx*16;
        } else {                             // W1
            int d = idx - 2048;
            int wvd = d >> 10, kk = (d >> 6) & 15, ln = d & 63;
            s = Wr1 + (size_t)(p0 + (ln & 15))*KCAT + wvd*512 + kk*32 + (ln >> 4)*8;
            dst = smem + 32768 + d*16;
        }
        *reinterpret_cast<f16x8*>(dst) = *reinterpret_cast<const f16x8*>(s);
    }
    __syncthreads();

    f32x4 cst = {0.f,0.f,0.f,0.f};
    f32x4 ho_keep = {0.f,0.f,0.f,0.f};
    f32x4 bias[4];
    {
        const float* bsrc = (wv == 0) ? br0 : br1;
        #pragma unroll
        for (int jj = 0; jj < 4; ++jj)
            bias[jj] = *reinterpret_cast<const f32x4*>(&bsrc[p0 + jj*4]);
    }

    const int kofs = (wv & 1)*512 + q*8;
    const int wcol = wv*512 + q*8;
    const char* wh0frag = smem + (wv >= 2 ? (wv-2)*16384 : 0) + lane*16;
    const char* w1frag  = smem + 32768 + wv*16384 + lane*16;
    const size_t BH = (size_t)BATCH*HID;

    for (int k = 0; k <= SEQ; ++k){
        // ---------------- PHASE 1 ----------------
        f32x4 acc[4];
        #pragma unroll
        for (int m = 0; m < 4; ++m){ acc[m].x=0;acc[m].y=0;acc[m].z=0;acc[m].w=0; }

        if (wv < 2){
            if (k < SEQ){
                if (use_xf16)
                    gemm_asm_gb(xbf + (size_t)k*BH + (size_t)r*HID + kofs,
                                Wr0 + (size_t)(p0 + r)*KCAT + wcol, acc);
                else
                    gemm_q_f32(xf32 + (size_t)k*BH + (size_t)r*HID + kofs,
                               Wr0 + (size_t)(p0 + r)*KCAT + wcol, acc);
            }
        } else {
            if (k > 0){
                if (wg == 0 && wv == 3) aggregate_publish(flags, F0_BASE, E0_IDX, k, lane);
                else                    wait_epoch_g(flags, E0_IDX, k, rep);
            }
            if (k < SEQ){
                const _Float16* A0 = (k == 0) ? (hz + (size_t)r*HID + kofs)
                                              : (h0ring + (size_t)(k-1)*BH + (size_t)r*HID + kofs);
                gemm_asm_ldsb(A0, wh0frag, acc);
            }
        }

        #pragma unroll
        for (int mt = 0; mt < 4; ++mt)
            #pragma unroll
            for (int j = 0; j < 4; ++j)
                accL[0][wv][mt*16 + q*4 + j][r] = acc[mt][j];
        __syncthreads();   // SYNC_A

        if (wv == 0 && k < SEQ){
            f32x4 zz[4];
            #pragma unroll
            for (int jj = 0; jj < 4; ++jj) zz[jj] = bias[jj];
            #pragma unroll
            for (int w2 = 0; w2 < 4; ++w2)
                #pragma unroll
                for (int jj = 0; jj < 4; ++jj){
                    f32x4 a = *reinterpret_cast<const f32x4*>(&accL[0][w2][lane][jj*4]);
                    zz[jj].x += a.x; zz[jj].y += a.y; zz[jj].z += a.z; zz[jj].w += a.w;
                }
            f16x4 hv;
            #pragma unroll
            for (int jl = 0; jl < 4; ++jl){
                float ig = sigm_f(zz[jl].x), fg = sigm_f(zz[jl].y);
                float gg = tanh_f(zz[jl].z), og = sigm_f(zz[jl].w);
                float c = fg*cst[jl] + ig*gg;  cst[jl] = c;
                hv[jl] = (_Float16)(og * tanh_f(c));
            }
            store_h8(h0ring + ((size_t)k*BATCH + lane)*HID + wg*4, hv);
            drain_vmem();
            if (lane == 0)
                __hip_atomic_store(&flags[F0_BASE + wg*32], k + 1,
                                   __ATOMIC_RELAXED, __HIP_MEMORY_SCOPE_AGENT);
        }

        // ---------------- PHASE 2 ----------------
        #pragma unroll
        for (int m = 0; m < 4; ++m){ acc[m].x=0;acc[m].y=0;acc[m].z=0;acc[m].w=0; }

        if (k >= 1){
            if (wv < 2){
                // SYNC_A implies epoch0 >= k (wv2/3 observed it) -> no wait
                gemm_asm_ldsb(h0ring + (size_t)(k-1)*BH + (size_t)r*HID + kofs,
                              w1frag, acc);
            } else {
                if (k >= 2){
                    if (wg == 0 && wv == 2) aggregate_publish(flags, F1_BASE, E1_IDX, k-1, lane);
                    else                    wait_epoch_g(flags, E1_IDX, k-1, rep);
                }
                const _Float16* A1 = (k == 1) ? (hz + (size_t)r*HID + kofs)
                                              : (h1ring + (size_t)(k-2)*BH + (size_t)r*HID + kofs);
                gemm_asm_ldsb(A1, w1frag, acc);
            }
        }

        #pragma unroll
        for (int mt = 0; mt < 4; ++mt)
            #pragma unroll
            for (int j = 0; j < 4; ++j)
                accL[1][wv][mt*16 + q*4 + j][r] = acc[mt][j];
        __syncthreads();   // SYNC_B

        if (wv == 1 && k >= 1){
            const int t1 = k - 1;
            f32x4 zz[4];
            #pragma unroll
            for (int jj = 0; jj < 4; ++jj) zz[jj] = bias[jj];
            #pragma unroll
            for (int w2 = 0; w2 < 4; ++w2)
                #pragma unroll
                for (int jj = 0; jj < 4; ++jj){
                    f32x4 a = *reinterpret_cast<const f32x4*>(&accL[1][w2][lane][jj*4]);
                    zz[jj].x += a.x; zz[jj].y += a.y; zz[jj].z += a.z; zz[jj].w += a.w;
                }
            f16x4 hv; f32x4 ho;
            #pragma unroll
            for (int jl = 0; jl < 4; ++jl){
                float ig = sigm_f(zz[jl].x), fg = sigm_f(zz[jl].y);
                float gg = tanh_f(zz[jl].z), og = sigm_f(zz[jl].w);
                float c = fg*cst[jl] + ig*gg;  cst[jl] = c;
                float h = og * tanh_f(c);
                hv[jl] = (_Float16)h;  ho[jl] = h;
            }
            if (k < SEQ) store_h8(h1ring + ((size_t)t1*BATCH + lane)*HID + wg*4, hv);
            if (t1 < SEQ-1) *reinterpret_cast<f32x4*>(out + ((size_t)t1*BATCH + lane)*HID + wg*4) = ho;
            else            ho_keep = ho;   // out[511] deferred (alias safety)
            drain_vmem();
            if (lane == 0)
                __hip_atomic_store(&flags[F1_BASE + wg*32], k,
                                   __ATOMIC_RELAXED, __HIP_MEMORY_SCOPE_AGENT);
        }
    }

    // epilogue (R9-verified): flag0=SEQ+1 after all local reads of h0[511]
    if (tid == 0)
        __hip_atomic_store(&flags[F0_BASE + wg*32], SEQ + 1,
                           __ATOMIC_RELAXED, __HIP_MEMORY_SCOPE_AGENT);
    if (wg == 0 && wv == 3) aggregate_publish(flags, F0_BASE, E0_IDX, SEQ + 1, lane);
    if (wv == 1){
        wait_epoch_g(flags, E0_IDX, SEQ + 1, rep);
        *reinterpret_cast<f32x4*>(out + ((size_t)(SEQ-1)*BATCH + lane)*HID + wg*4) = ho_keep;
    }
}

// ---------------- host launcher ----------------

extern "C" void kernel_launch(void* const* d_in, const int* in_sizes, int n_in,
                              void* d_out, int out_size, void* d_ws, size_t ws_size,
                              hipStream_t stream){
    const float* x   = (const float*)d_in[0];
    const float* Wx0 = (const float*)d_in[1];
    const float* bx0 = (const float*)d_in[2];
    const float* Wh0 = (const float*)d_in[3];
    const float* bh0 = (const float*)d_in[4];
    const float* Wx1 = (const float*)d_in[5];
    const float* bx1 = (const float*)d_in[6];
    const float* Wh1 = (const float*)d_in[7];
    const float* bh1 = (const float*)d_in[8];
    float* out = (float*)d_out;
    char* ws = (char*)d_ws;

    size_t o = 0;
    _Float16* Wr0 = (_Float16*)(ws + o); o += (size_t)NG*KCAT*2;
    _Float16* Wr1 = (_Float16*)(ws + o); o += (size_t)NG*KCAT*2;
    float* br0 = (float*)(ws + o); o += 16384;
    float* br1 = (float*)(ws + o); o += 16384;
    _Float16* h1ring = (_Float16*)(ws + o); o += (size_t)SEQ*BATCH*HID*2;
    _Float16* hz     = (_Float16*)(ws + o); o += (size_t)BATCH*HID*2;
    int* flags = (int*)(ws + o); o += 131072;

    const size_t RING = (size_t)SEQ*BATCH*HID*2;
    _Float16 *xbf = nullptr, *h0ring;
    int use_xf16 = 0;
    if (ws_size >= o + 2*RING){
        xbf    = (_Float16*)(ws + o);  o += RING;  use_xf16 = 1;
        h0ring = (_Float16*)(ws + o);  o += RING;
    } else if (ws_size >= o + RING){
        xbf    = (_Float16*)(ws + o);  o += RING;  use_xf16 = 1;
        h0ring = (_Float16*)((char*)d_out + (size_t)64*1024*1024);
    } else {
        h0ring = (_Float16*)((char*)d_out + (size_t)64*1024*1024);
    }

    hipFuncSetAttribute((const void*)lstm_persist,
                        hipFuncAttributeMaxDynamicSharedMemorySize, SMEM_BYTES);

    prep_w_kernel<<<NG, 256, 0, stream>>>(Wx0, Wh0, bx0, bh0, Wr0, br0);
    prep_w_kernel<<<NG, 256, 0, stream>>>(Wx1, Wh1, bx1, bh1, Wr1, br1);
    if (use_xf16)
        prep_x_kernel<<<(SEQ*BATCH*HID)/(256*8), 256, 0, stream>>>(x, xbf);
    init_misc_kernel<<<128, 256, 0, stream>>>(flags, hz);
    lstm_persist<<<256, 256, SMEM_BYTES, stream>>>(Wr0, Wr1, br0, br1, xbf, x, use_xf16,
                                                   hz, h0ring, h1ring, out, flags);
}